// Round 13
// baseline (218.205 us; speedup 1.0000x reference)
//
#include <hip/hip_runtime.h>
#include <hip/hip_bf16.h>
#include <cmath>

using bf16 = __hip_bfloat16;
typedef __attribute__((ext_vector_type(4))) float  f32x4;
typedef __attribute__((ext_vector_type(8))) short  bf16x8;
typedef unsigned int u32;
typedef unsigned short u16;

// async global->LDS, 16B per lane
__device__ __forceinline__ void gl_lds16(const bf16* g, bf16* l) {
    __builtin_amdgcn_global_load_lds(
        (const __attribute__((address_space(1))) u32*)g,
        (__attribute__((address_space(3))) u32*)l, 16, 0, 0);
}

__device__ __forceinline__ u32 pk2(float a, float b) {
    bf16 ha = __float2bfloat16(a), hb = __float2bfloat16(b);
    return (u32)*(u16*)&ha | ((u32)*(u16*)&hb << 16);
}
__device__ __forceinline__ float b2f(u16 v) {
    return __uint_as_float((u32)v << 16);
}

// ---------------------------------------------------------------------------
// Q projection: full 256-o tile (x read ONCE), fused transpose-convert. (R9)
// grid (32 s-tiles, 16 b), block 512.
// ---------------------------------------------------------------------------
__global__ __launch_bounds__(512) void qproj8(
    const float* __restrict__ x,   // [16][256][4096]
    const bf16* __restrict__ Wq,   // [256][256]
    bf16* __restrict__ qch)        // [16][256][4096]
{
    __shared__ __align__(16) bf16 sW[256 * 64];
    __shared__ __align__(16) bf16 sX[128 * 72];
    const int t = threadIdx.x;
    const int lane = t & 63, wid = t >> 6;
    const int wm = wid >> 1, wn = wid & 1;
    const int g = lane >> 4, lr = lane & 15;
    const int s0 = blockIdx.x * 128;
    const int b = blockIdx.y;
    const float* xb = x + (long)b * 1048576;

    f32x4 acc[4][4];
#pragma unroll
    for (int i = 0; i < 4; ++i)
#pragma unroll
        for (int j = 0; j < 4; ++j) acc[i][j] = (f32x4){0.f, 0.f, 0.f, 0.f};

    const int p  = t & 31;
    const int sl = t >> 5;

    for (int c0 = 0; c0 < 256; c0 += 64) {
        __syncthreads();
#pragma unroll
        for (int i = 0; i < 4; ++i) {
            int lin = i * 512 + t, r = lin >> 3, ch = lin & 7;
            gl_lds16(Wq + (long)r * 256 + c0 + ((ch ^ (r & 7)) << 3), &sW[lin * 8]);
        }
#pragma unroll
        for (int j = 0; j < 2; ++j) {
            int s4 = j * 16 + sl;
            const float* src = xb + (long)(c0 + 2 * p) * 4096 + s0 + s4 * 4;
            float4 a = *(const float4*)src;
            float4 bq = *(const float4*)(src + 4096);
            char* base = (char*)sX + p * 4 + (s4 * 4) * 144;
            *(u32*)(base +   0) = pk2(a.x, bq.x);
            *(u32*)(base + 144) = pk2(a.y, bq.y);
            *(u32*)(base + 288) = pk2(a.z, bq.z);
            *(u32*)(base + 432) = pk2(a.w, bq.w);
        }
        __syncthreads();
#pragma unroll
        for (int kk = 0; kk < 2; ++kk) {
            bf16x8 aw[4], fx[4];
#pragma unroll
            for (int mf = 0; mf < 4; ++mf) {
                int r = wm * 64 + mf * 16 + lr;
                aw[mf] = *(const bf16x8*)((const char*)sW + r * 128 + (((kk * 4 + g) ^ (r & 7)) << 4));
            }
#pragma unroll
            for (int nf = 0; nf < 4; ++nf) {
                int s = wn * 64 + nf * 16 + lr;
                fx[nf] = *(const bf16x8*)((const char*)sX + s * 144 + (kk * 4 + g) * 16);
            }
#pragma unroll
            for (int mf = 0; mf < 4; ++mf)
#pragma unroll
                for (int nf = 0; nf < 4; ++nf)
                    acc[mf][nf] = __builtin_amdgcn_mfma_f32_16x16x32_bf16(
                        aw[mf], fx[nf], acc[mf][nf], 0, 0, 0);
        }
    }
    bf16* qb = qch + (long)b * 1048576;
#pragma unroll
    for (int mf = 0; mf < 4; ++mf)
#pragma unroll
        for (int nf = 0; nf < 4; ++nf)
#pragma unroll
            for (int e = 0; e < 4; ++e) {
                int o = wm * 64 + mf * 16 + g * 4 + e;
                int s = s0 + wn * 64 + nf * 16 + lr;
                qb[(long)o * 4096 + s] = __float2bfloat16(acc[mf][nf][e]);
            }
}

// ---------------------------------------------------------------------------
// K+V projection, fused transpose-convert, double-buffered fm; weights as
// direct-global fragments (L2-hot, pvffn-proven pattern).  LDS 36 KB.
// grid (32 s-tiles, 64 bn), block 256 (4 waves).
// ---------------------------------------------------------------------------
__global__ __launch_bounds__(256, 3) void kvproj(
    const float* __restrict__ fm,  // [64][256][4096]
    const bf16* __restrict__ Wk,   // [4][64][256]
    const bf16* __restrict__ Wv,   // [4][64][256]
    bf16* __restrict__ kb,         // [64][64][4096]
    bf16* __restrict__ vT)         // [64][4096][64]
{
    __shared__ bf16 sF[2][128 * 72];   // [s][c], 144-B rows; 36 KB total
    const int t = threadIdx.x;
    const int lane = t & 63, wid = t >> 6;
    const int g = lane >> 4, lr = lane & 15;
    const int s0 = blockIdx.x * 128;
    const int bn = blockIdx.y, n = bn & 3;
    const float* fb = fm + (long)bn * 1048576;
    const bf16* WkN = Wk + (long)n * 16384;
    const bf16* WvN = Wv + (long)n * 16384;

    f32x4 acc1[4][2];
    f32x4 acc2[2][4];
#pragma unroll
    for (int i = 0; i < 4; ++i)
#pragma unroll
        for (int j = 0; j < 2; ++j) {
            acc1[i][j] = (f32x4){0.f, 0.f, 0.f, 0.f};
            acc2[j][i] = (f32x4){0.f, 0.f, 0.f, 0.f};
        }

    const int p  = t & 31;
    const int sl = t >> 5;

    // prologue: stage fm c0=0 tile into buf 0
    {
        float4 ra[4], rb[4];
#pragma unroll
        for (int j = 0; j < 4; ++j) {
            const float* src = fb + (long)(2 * p) * 4096 + s0 + (j * 8 + sl) * 4;
            ra[j] = *(const float4*)src;
            rb[j] = *(const float4*)(src + 4096);
        }
#pragma unroll
        for (int j = 0; j < 4; ++j) {
            char* base = (char*)&sF[0][0] + p * 4 + ((j * 8 + sl) * 4) * 144;
            *(u32*)(base +   0) = pk2(ra[j].x, rb[j].x);
            *(u32*)(base + 144) = pk2(ra[j].y, rb[j].y);
            *(u32*)(base + 288) = pk2(ra[j].z, rb[j].z);
            *(u32*)(base + 432) = pk2(ra[j].w, rb[j].w);
        }
        __syncthreads();
    }

    int cur = 0;
    for (int it = 0; it < 4; ++it) {
        const int c0 = it * 64;
        const int c0n = c0 + 64;
        float4 ra[4], rb[4];
        if (it < 3) {
#pragma unroll
            for (int j = 0; j < 4; ++j) {
                const float* src = fb + (long)(c0n + 2 * p) * 4096 + s0 + (j * 8 + sl) * 4;
                ra[j] = *(const float4*)src;
                rb[j] = *(const float4*)(src + 4096);
            }
        }
        const char* fbase = (const char*)&sF[cur][0];
#pragma unroll
        for (int kk = 0; kk < 2; ++kk) {
            // weight fragments direct from global (L2-hot)
            bf16x8 ak[4], ff[2], bv[4];
            const int ko = c0 + (kk * 4 + g) * 8;
#pragma unroll
            for (int mf = 0; mf < 4; ++mf)
                ak[mf] = *(const bf16x8*)(WkN + (mf * 16 + lr) * 256 + ko);
#pragma unroll
            for (int nf = 0; nf < 4; ++nf)
                bv[nf] = *(const bf16x8*)(WvN + (nf * 16 + lr) * 256 + ko);
#pragma unroll
            for (int i = 0; i < 2; ++i) {
                int s = wid * 32 + i * 16 + lr;
                ff[i] = *(const bf16x8*)(fbase + s * 144 + (kk * 4 + g) * 16);
            }
#pragma unroll
            for (int mf = 0; mf < 4; ++mf)
#pragma unroll
                for (int i = 0; i < 2; ++i)
                    acc1[mf][i] = __builtin_amdgcn_mfma_f32_16x16x32_bf16(
                        ak[mf], ff[i], acc1[mf][i], 0, 0, 0);
#pragma unroll
            for (int i = 0; i < 2; ++i)
#pragma unroll
                for (int nf = 0; nf < 4; ++nf)
                    acc2[i][nf] = __builtin_amdgcn_mfma_f32_16x16x32_bf16(
                        ff[i], bv[nf], acc2[i][nf], 0, 0, 0);
        }
        if (it < 3) {
#pragma unroll
            for (int j = 0; j < 4; ++j) {
                char* base = (char*)&sF[cur ^ 1][0] + p * 4 + ((j * 8 + sl) * 4) * 144;
                *(u32*)(base +   0) = pk2(ra[j].x, rb[j].x);
                *(u32*)(base + 144) = pk2(ra[j].y, rb[j].y);
                *(u32*)(base + 288) = pk2(ra[j].z, rb[j].z);
                *(u32*)(base + 432) = pk2(ra[j].w, rb[j].w);
            }
            __syncthreads();
            cur ^= 1;
        }
    }

    bf16* kbb = kb + (long)bn * 262144;
#pragma unroll
    for (int mf = 0; mf < 4; ++mf)
#pragma unroll
        for (int i = 0; i < 2; ++i)
#pragma unroll
            for (int e = 0; e < 4; ++e) {
                int dd = mf * 16 + g * 4 + e;
                int s  = s0 + wid * 32 + i * 16 + lr;
                kbb[(long)dd * 4096 + s] = __float2bfloat16(acc1[mf][i][e]);
            }
    bf16* vtb = vT + (long)bn * 262144;
#pragma unroll
    for (int i = 0; i < 2; ++i)
#pragma unroll
        for (int nf = 0; nf < 4; ++nf)
#pragma unroll
            for (int e = 0; e < 4; ++e) {
                int s = s0 + wid * 32 + i * 16 + g * 4 + e;
                int ec = nf * 16 + lr;
                vtb[(long)s * 64 + ec] = __float2bfloat16(acc2[i][nf][e]);
            }
}

// ---------------------------------------------------------------------------
// QK^T partial + fused row sum-of-squares, 8 chunks, double-buffered. (R5)
// grid (8, 64), block 256.
// ---------------------------------------------------------------------------
__global__ __launch_bounds__(256) void qk_sum(
    const bf16* __restrict__ kb,   // [64][64][4096]
    const bf16* __restrict__ qch,  // viewed as [64][64][4096]
    float* __restrict__ part,      // [64][8][64][64]
    float* __restrict__ sumq, float* __restrict__ sumk)  // [8][4096]
{
    __shared__ bf16 sA[2][64 * 64];
    __shared__ bf16 sB[2][64 * 64];
    const int t = threadIdx.x;
    const int lane = t & 63, wid = t >> 6;
    const int wm = wid >> 1, wn = wid & 1;
    const int g = lane >> 4, lr = lane & 15;
    const int ch_ = blockIdx.x;
    const int bn = blockIdx.y;
    const bf16* kbase = kb + (long)bn * 262144;
    const bf16* qbase = qch + (long)bn * 262144;

    const int srow = t >> 1;
    const int shalf = t & 1;

    f32x4 acc[2][2];
#pragma unroll
    for (int i = 0; i < 2; ++i)
#pragma unroll
        for (int j = 0; j < 2; ++j) acc[i][j] = (f32x4){0.f, 0.f, 0.f, 0.f};
    float ss = 0.f;

    {
        int k0 = ch_ * 512;
#pragma unroll
        for (int i = 0; i < 2; ++i) {
            int lin = i * 256 + t, r = lin >> 3, c = lin & 7;
            gl_lds16(kbase + (long)r * 4096 + k0 + ((c ^ (r & 7)) << 3), &sA[0][lin * 8]);
            gl_lds16(qbase + (long)r * 4096 + k0 + ((c ^ (r & 7)) << 3), &sB[0][lin * 8]);
        }
        __syncthreads();
    }

    int cur = 0;
    for (int it = 0; it < 8; ++it) {
        if (it < 7) {
            int k0 = ch_ * 512 + (it + 1) * 64;
#pragma unroll
            for (int i = 0; i < 2; ++i) {
                int lin = i * 256 + t, r = lin >> 3, c = lin & 7;
                gl_lds16(kbase + (long)r * 4096 + k0 + ((c ^ (r & 7)) << 3), &sA[cur ^ 1][lin * 8]);
                gl_lds16(qbase + (long)r * 4096 + k0 + ((c ^ (r & 7)) << 3), &sB[cur ^ 1][lin * 8]);
            }
        }
        const char* abase = (const char*)&sA[cur][0];
        const char* bbase = (const char*)&sB[cur][0];
#pragma unroll
        for (int kk = 0; kk < 2; ++kk) {
            bf16x8 af[2], bf[2];
#pragma unroll
            for (int mf = 0; mf < 2; ++mf) {
                int r = wm * 32 + mf * 16 + lr;
                af[mf] = *(const bf16x8*)(abase + r * 128 + (((kk * 4 + g) ^ (r & 7)) << 4));
            }
#pragma unroll
            for (int nf = 0; nf < 2; ++nf) {
                int r = wn * 32 + nf * 16 + lr;
                bf[nf] = *(const bf16x8*)(bbase + r * 128 + (((kk * 4 + g) ^ (r & 7)) << 4));
            }
#pragma unroll
            for (int mf = 0; mf < 2; ++mf)
#pragma unroll
                for (int nf = 0; nf < 2; ++nf)
                    acc[mf][nf] = __builtin_amdgcn_mfma_f32_16x16x32_bf16(
                        af[mf], bf[nf], acc[mf][nf], 0, 0, 0);
        }
        {
            const char* base = (srow < 64) ? abase + srow * 128
                                           : bbase + (srow - 64) * 128;
            int r7 = srow & 7;
#pragma unroll
            for (int j = 0; j < 4; ++j) {
                bf16x8 v = *(const bf16x8*)(base + (((shalf * 4 + j) ^ r7) << 4));
#pragma unroll
                for (int e = 0; e < 8; ++e) {
                    float f = b2f((u16)v[e]);
                    ss += f * f;
                }
            }
        }
        __syncthreads();
        cur ^= 1;
    }

    ss += __shfl_xor(ss, 1);
    if (shalf == 0) {
        if (srow < 64) sumk[ch_ * 4096 + bn * 64 + srow] = ss;
        else           sumq[ch_ * 4096 + bn * 64 + srow - 64] = ss;
    }
    float* pp = part + ((long)bn * 8 + ch_) * 4096;
#pragma unroll
    for (int mf = 0; mf < 2; ++mf)
#pragma unroll
        for (int nf = 0; nf < 2; ++nf)
#pragma unroll
            for (int e = 0; e < 4; ++e) {
                int m = wm * 32 + mf * 16 + g * 4 + e;
                int nn = wn * 32 + nf * 16 + lr;
                pp[m * 64 + nn] = acc[mf][nf][e];
            }
}

// ---------------------------------------------------------------------------
// finalize: sum 8 partials, rsqrt norms, scale, softmax -> bf16  (R5)
// ---------------------------------------------------------------------------
__global__ __launch_bounds__(256) void attn_finalize_kernel(
    const float* __restrict__ part,
    const float* __restrict__ sumq, const float* __restrict__ sumk,
    const float* __restrict__ rescale,
    bf16* __restrict__ attn_out)
{
    const int bn = blockIdx.x;
    const int n = bn & 3;
    const int t = threadIdx.x;
    const float rs = rescale[n];

    __shared__ float att[64][65];
    __shared__ float rmax[64], rsum[64];
    __shared__ float iq[64], ik[64];

    if (t < 64) {
        float s = 0.f;
#pragma unroll
        for (int c = 0; c < 8; ++c) s += sumk[c * 4096 + bn * 64 + t];
        ik[t] = 1.f / fmaxf(sqrtf(s), 1e-12f);
    } else if (t < 128) {
        float s = 0.f;
#pragma unroll
        for (int c = 0; c < 8; ++c) s += sumq[c * 4096 + bn * 64 + t - 64];
        iq[t - 64] = 1.f / fmaxf(sqrtf(s), 1e-12f);
    }
    __syncthreads();

    const float* pb = part + (size_t)bn * 8 * 4096;
#pragma unroll
    for (int p = 0; p < 16; ++p) {
        int lin = p * 256 + t;
        int dd = lin >> 6, e = lin & 63;
        float v = 0.f;
#pragma unroll
        for (int c = 0; c < 8; ++c) v += pb[c * 4096 + lin];
        v *= ik[dd] * iq[e] * rs;
        att[dd][e] = v;
    }
    __syncthreads();
    if (t < 64) {
        float m = -1e30f;
        for (int e = 0; e < 64; ++e) m = fmaxf(m, att[t][e]);
        float sm = 0.f;
        for (int e = 0; e < 64; ++e) sm += expf(att[t][e] - m);
        rmax[t] = m;
        rsum[t] = 1.0f / sm;
    }
    __syncthreads();
    bf16* ob = attn_out + (size_t)bn * 4096;
#pragma unroll
    for (int p = 0; p < 16; ++p) {
        int lin = p * 256 + t;
        int dd = lin >> 6, e = lin & 63;
        ob[lin] = __float2bfloat16(expf(att[dd][e] - rmax[dd]) * rsum[dd]);
    }
}

// ---------------------------------------------------------------------------
// Fused PV + FFN, prefetched, 64-s tile. (R10)
// grid (64 s-tiles, 16 b), block 256. LDS 40 KB.
// ---------------------------------------------------------------------------
__global__ __launch_bounds__(256) void pvffn(
    const bf16* __restrict__ vT,    // [64][4096][64]
    const bf16* __restrict__ attnb, // [64][64][64]
    const bf16* __restrict__ qch,   // [16][256][4096]
    const bf16* __restrict__ Wf,    // [256][256]
    const float* __restrict__ bffn, // [256]
    float* __restrict__ out)        // [16][256][4096]
{
    __shared__ bf16 bufA[2][8192];
    __shared__ bf16 Zs[64 * 64];
    const int t = threadIdx.x;
    const int lane = t & 63, wid = t >> 6;
    const int g = lane >> 4, lr = lane & 15;
    const int s0 = blockIdx.x * 64;
    const int b = blockIdx.y;

    f32x4 accF[4][4];
#pragma unroll
    for (int i = 0; i < 4; ++i)
#pragma unroll
        for (int j = 0; j < 4; ++j) accF[i][j] = (f32x4){0.f, 0.f, 0.f, 0.f};

    {
        const int bn = b * 4;
#pragma unroll
        for (int i = 0; i < 2; ++i) {
            int lin = i * 256 + t, r = lin >> 3, c = lin & 7;
            gl_lds16(vT + (long)bn * 262144 + (long)(s0 + r) * 64 + ((c ^ (r & 7)) << 3),
                     &bufA[0][lin * 8]);
            gl_lds16(attnb + (long)bn * 4096 + r * 64 + ((c ^ (r & 7)) << 3),
                     &bufA[0][4096 + lin * 8]);
        }
        __syncthreads();
    }

    for (int n = 0; n < 4; ++n) {
        const int bn = b * 4 + n;
        const int cur = n & 1;
        if (n < 3) {
            const int bnn = bn + 1;
#pragma unroll
            for (int i = 0; i < 2; ++i) {
                int lin = i * 256 + t, r = lin >> 3, c = lin & 7;
                gl_lds16(vT + (long)bnn * 262144 + (long)(s0 + r) * 64 + ((c ^ (r & 7)) << 3),
                         &bufA[cur ^ 1][lin * 8]);
                gl_lds16(attnb + (long)bnn * 4096 + r * 64 + ((c ^ (r & 7)) << 3),
                         &bufA[cur ^ 1][4096 + lin * 8]);
            }
        }
        bf16x8 wf[2][4];
#pragma unroll
        for (int kk = 0; kk < 2; ++kk)
#pragma unroll
            for (int mf = 0; mf < 4; ++mf)
                wf[kk][mf] = *(const bf16x8*)(
                    Wf + (long)(wid * 64 + mf * 16 + lr) * 256 + n * 64 + (kk * 4 + g) * 8);

        const char* vb = (const char*)&bufA[cur][0];
        const char* ab = vb + 8192;
        f32x4 accP[4];
#pragma unroll
        for (int j = 0; j < 4; ++j) accP[j] = (f32x4){0.f, 0.f, 0.f, 0.f};
#pragma unroll
        for (int kk = 0; kk < 2; ++kk) {
            int r = wid * 16 + lr;
            bf16x8 av = *(const bf16x8*)(vb + r * 128 + (((kk * 4 + g) ^ (r & 7)) << 4));
            bf16x8 at[4];
#pragma unroll
            for (int nf = 0; nf < 4; ++nf) {
                int rr = nf * 16 + lr;
                at[nf] = *(const bf16x8*)(ab + rr * 128 + (((kk * 4 + g) ^ (rr & 7)) << 4));
            }
#pragma unroll
            for (int nf = 0; nf < 4; ++nf)
                accP[nf] = __builtin_amdgcn_mfma_f32_16x16x32_bf16(
                    av, at[nf], accP[nf], 0, 0, 0);
        }
#pragma unroll
        for (int nf = 0; nf < 4; ++nf) {
            int slb = wid * 16 + g * 4;
            int il = nf * 16 + lr;
            ushort4 qv = *(const ushort4*)(qch + ((long)b * 256 + n * 64 + il) * 4096 + s0 + slb);
            u16 qa[4] = {qv.x, qv.y, qv.z, qv.w};
#pragma unroll
            for (int e = 0; e < 4; ++e) {
                int sl = slb + e;
                float v = accP[nf][e] + b2f(qa[e]);
                bf16 hv = __float2bfloat16(v);
                int byte = sl * 128 + ((((il >> 3) ^ (sl & 7))) << 4) + (il & 7) * 2;
                *(u16*)((char*)Zs + byte) = *(u16*)&hv;
            }
        }
        __syncthreads();
#pragma unroll
        for (int kk = 0; kk < 2; ++kk) {
            bf16x8 bz[4];
#pragma unroll
            for (int nf = 0; nf < 4; ++nf) {
                int sl = nf * 16 + lr;
                bz[nf] = *(const bf16x8*)((const char*)Zs + sl * 128 + (((kk * 4 + g) ^ (sl & 7)) << 4));
            }
#pragma unroll
            for (int mf = 0; mf < 4; ++mf)
#pragma unroll
                for (int nf = 0; nf < 4; ++nf)
                    accF[mf][nf] = __builtin_amdgcn_mfma_f32_16x16x32_bf16(
                        wf[kk][mf], bz[nf], accF[mf][nf], 0, 0, 0);
        }
        __syncthreads();
    }

    float* ob = out + (long)b * 1048576;
    const bf16* qb = qch + (long)b * 1048576;
#pragma unroll
    for (int mf = 0; mf < 4; ++mf)
#pragma unroll
        for (int e = 0; e < 4; ++e) {
            int c = wid * 64 + mf * 16 + g * 4 + e;
            float bv = bffn[c];
#pragma unroll
            for (int nf = 0; nf < 4; ++nf) {
                int s = s0 + nf * 16 + lr;
                long idx = (long)c * 4096 + s;
                ob[idx] = accF[mf][nf][e] + bv + b2f(*(const u16*)(qb + idx));
            }
        }
}

// ---------------------------------------------------------------------------
__global__ __launch_bounds__(256) void wconv(
    const float* __restrict__ a, const float* __restrict__ b,
    const float* __restrict__ c, const float* __restrict__ d,
    bf16* __restrict__ o)
{
    int i = blockIdx.x * 256 + threadIdx.x;
    int which = i >> 16, off = i & 65535;
    const float* s = (which == 0) ? a : (which == 1) ? b : (which == 2) ? c : d;
    o[i] = __float2bfloat16(s[off]);
}

// ---------------------------------------------------------------------------
extern "C" void kernel_launch(void* const* d_in, const int* in_sizes, int n_in,
                              void* d_out, int out_size, void* d_ws, size_t ws_size,
                              hipStream_t stream) {
    const float* x       = (const float*)d_in[0];
    const float* fmaps   = (const float*)d_in[1];
    const float* Wq      = (const float*)d_in[2];
    const float* Wk      = (const float*)d_in[3];
    const float* Wv      = (const float*)d_in[4];
    const float* rescale = (const float*)d_in[5];
    const float* Wffn    = (const float*)d_in[6];
    const float* bffn    = (const float*)d_in[7];
    float* out = (float*)d_out;

    char* w = (char*)d_ws;
    bf16* kbuf  = (bf16*)(w + 0);             // 33.55 MB
    bf16* vT    = (bf16*)(w + 33554432L);     // 33.55 MB
    bf16* qch   = (bf16*)(w + 67108864L);     // 33.55 MB
    float* part = (float*)(w + 100663296L);   // 8.39 MB
    bf16* attnb = (bf16*)(w + 109051904L);    // 512 KB
    float* sumq = (float*)(w + 109576192L);   // 128 KB
    float* sumk = (float*)(w + 109707264L);   // 128 KB
    bf16* Wq_b  = (bf16*)(w + 109838336L);
    bf16* Wk_b  = Wq_b + 65536;
    bf16* Wv_b  = Wq_b + 131072;
    bf16* Wf_b  = Wq_b + 196608;

    dim3 blk(256);

    // 1. weights -> bf16
    wconv<<<dim3(1024), blk, 0, stream>>>(Wq, Wk, Wv, Wffn, Wq_b);
    // 2. K/V projections, fmaps read once (weights direct-global, 36 KB LDS)
    kvproj<<<dim3(32, 64), blk, 0, stream>>>(fmaps, Wk_b, Wv_b, kbuf, vT);
    // 3. Q projection (256-o tile: x read once)
    qproj8<<<dim3(32, 16), dim3(512), 0, stream>>>(x, Wq_b, qch);
    // 4. QK^T partials + fused row sumsq
    qk_sum<<<dim3(8, 64), blk, 0, stream>>>(kbuf, qch, part, sumq, sumk);
    // 5. finalize: rsqrt + scale + softmax -> attn bf16
    attn_finalize_kernel<<<dim3(64), blk, 0, stream>>>(part, sumq, sumk, rescale, attnb);
    // 6. fused PV + FFN -> out f32
    pvffn<<<dim3(64, 16), blk, 0, stream>>>(vT, attnb, qch, Wf_b, bffn, out);
}

// Round 14
// 179.812 us; speedup vs baseline: 1.2135x; 1.2135x over previous
//
#include <hip/hip_runtime.h>
#include <hip/hip_bf16.h>
#include <cmath>

using bf16 = __hip_bfloat16;
typedef __attribute__((ext_vector_type(4))) float  f32x4;
typedef __attribute__((ext_vector_type(8))) short  bf16x8;
typedef unsigned int u32;
typedef unsigned short u16;

// async global->LDS, 16B per lane
__device__ __forceinline__ void gl_lds16(const bf16* g, bf16* l) {
    __builtin_amdgcn_global_load_lds(
        (const __attribute__((address_space(1))) u32*)g,
        (__attribute__((address_space(3))) u32*)l, 16, 0, 0);
}

__device__ __forceinline__ u32 pk2(float a, float b) {
    bf16 ha = __float2bfloat16(a), hb = __float2bfloat16(b);
    return (u32)*(u16*)&ha | ((u32)*(u16*)&hb << 16);
}
__device__ __forceinline__ float b2f(u16 v) {
    return __uint_as_float((u32)v << 16);
}

// ---------------------------------------------------------------------------
// Q projection: full 256-o tile (x read ONCE), fused transpose-convert. (R9)
// grid (32 s-tiles, 16 b), block 512.
// ---------------------------------------------------------------------------
__global__ __launch_bounds__(512) void qproj8(
    const float* __restrict__ x,   // [16][256][4096]
    const bf16* __restrict__ Wq,   // [256][256]
    bf16* __restrict__ qch)        // [16][256][4096]
{
    __shared__ __align__(16) bf16 sW[256 * 64];
    __shared__ __align__(16) bf16 sX[128 * 72];
    const int t = threadIdx.x;
    const int lane = t & 63, wid = t >> 6;
    const int wm = wid >> 1, wn = wid & 1;
    const int g = lane >> 4, lr = lane & 15;
    const int s0 = blockIdx.x * 128;
    const int b = blockIdx.y;
    const float* xb = x + (long)b * 1048576;

    f32x4 acc[4][4];
#pragma unroll
    for (int i = 0; i < 4; ++i)
#pragma unroll
        for (int j = 0; j < 4; ++j) acc[i][j] = (f32x4){0.f, 0.f, 0.f, 0.f};

    const int p  = t & 31;
    const int sl = t >> 5;

    for (int c0 = 0; c0 < 256; c0 += 64) {
        __syncthreads();
#pragma unroll
        for (int i = 0; i < 4; ++i) {
            int lin = i * 512 + t, r = lin >> 3, ch = lin & 7;
            gl_lds16(Wq + (long)r * 256 + c0 + ((ch ^ (r & 7)) << 3), &sW[lin * 8]);
        }
#pragma unroll
        for (int j = 0; j < 2; ++j) {
            int s4 = j * 16 + sl;
            const float* src = xb + (long)(c0 + 2 * p) * 4096 + s0 + s4 * 4;
            float4 a = *(const float4*)src;
            float4 bq = *(const float4*)(src + 4096);
            char* base = (char*)sX + p * 4 + (s4 * 4) * 144;
            *(u32*)(base +   0) = pk2(a.x, bq.x);
            *(u32*)(base + 144) = pk2(a.y, bq.y);
            *(u32*)(base + 288) = pk2(a.z, bq.z);
            *(u32*)(base + 432) = pk2(a.w, bq.w);
        }
        __syncthreads();
#pragma unroll
        for (int kk = 0; kk < 2; ++kk) {
            bf16x8 aw[4], fx[4];
#pragma unroll
            for (int mf = 0; mf < 4; ++mf) {
                int r = wm * 64 + mf * 16 + lr;
                aw[mf] = *(const bf16x8*)((const char*)sW + r * 128 + (((kk * 4 + g) ^ (r & 7)) << 4));
            }
#pragma unroll
            for (int nf = 0; nf < 4; ++nf) {
                int s = wn * 64 + nf * 16 + lr;
                fx[nf] = *(const bf16x8*)((const char*)sX + s * 144 + (kk * 4 + g) * 16);
            }
#pragma unroll
            for (int mf = 0; mf < 4; ++mf)
#pragma unroll
                for (int nf = 0; nf < 4; ++nf)
                    acc[mf][nf] = __builtin_amdgcn_mfma_f32_16x16x32_bf16(
                        aw[mf], fx[nf], acc[mf][nf], 0, 0, 0);
        }
    }
    bf16* qb = qch + (long)b * 1048576;
#pragma unroll
    for (int mf = 0; mf < 4; ++mf)
#pragma unroll
        for (int nf = 0; nf < 4; ++nf)
#pragma unroll
            for (int e = 0; e < 4; ++e) {
                int o = wm * 64 + mf * 16 + g * 4 + e;
                int s = s0 + wn * 64 + nf * 16 + lr;
                qb[(long)o * 4096 + s] = __float2bfloat16(acc[mf][nf][e]);
            }
}

// ---------------------------------------------------------------------------
// K+V projection, fused transpose-convert of fmaps, double-buffered. (R5)
// grid (32 s-tiles, 64 bn), block 256.
// ---------------------------------------------------------------------------
__global__ __launch_bounds__(256) void kvproj(
    const float* __restrict__ fm,  // [64][256][4096]
    const bf16* __restrict__ Wk,   // [4][64][256]
    const bf16* __restrict__ Wv,   // [4][64][256]
    bf16* __restrict__ kb,         // [64][64][4096]
    bf16* __restrict__ vT)         // [64][4096][64]
{
    __shared__ bf16 sF[2][128 * 72];
    __shared__ bf16 sK[2][64 * 64];
    __shared__ bf16 sV[2][64 * 64];
    const int t = threadIdx.x;
    const int lane = t & 63, wid = t >> 6;
    const int g = lane >> 4, lr = lane & 15;
    const int s0 = blockIdx.x * 128;
    const int bn = blockIdx.y, n = bn & 3;
    const float* fb = fm + (long)bn * 1048576;
    const bf16* WkN = Wk + (long)n * 16384;
    const bf16* WvN = Wv + (long)n * 16384;

    f32x4 acc1[4][2];
    f32x4 acc2[2][4];
#pragma unroll
    for (int i = 0; i < 4; ++i)
#pragma unroll
        for (int j = 0; j < 2; ++j) {
            acc1[i][j] = (f32x4){0.f, 0.f, 0.f, 0.f};
            acc2[j][i] = (f32x4){0.f, 0.f, 0.f, 0.f};
        }

    const int p  = t & 31;
    const int sl = t >> 5;

    {
#pragma unroll
        for (int i = 0; i < 2; ++i) {
            int lin = i * 256 + t, r = lin >> 3, ch = lin & 7;
            int off = r * 256 + ((ch ^ (r & 7)) << 3);
            gl_lds16(WkN + off, &sK[0][lin * 8]);
            gl_lds16(WvN + off, &sV[0][lin * 8]);
        }
        float4 ra[4], rb[4];
#pragma unroll
        for (int j = 0; j < 4; ++j) {
            const float* src = fb + (long)(2 * p) * 4096 + s0 + (j * 8 + sl) * 4;
            ra[j] = *(const float4*)src;
            rb[j] = *(const float4*)(src + 4096);
        }
#pragma unroll
        for (int j = 0; j < 4; ++j) {
            char* base = (char*)&sF[0][0] + p * 4 + ((j * 8 + sl) * 4) * 144;
            *(u32*)(base +   0) = pk2(ra[j].x, rb[j].x);
            *(u32*)(base + 144) = pk2(ra[j].y, rb[j].y);
            *(u32*)(base + 288) = pk2(ra[j].z, rb[j].z);
            *(u32*)(base + 432) = pk2(ra[j].w, rb[j].w);
        }
        __syncthreads();
    }

    int cur = 0;
    for (int it = 0; it < 4; ++it) {
        const int c0n = (it + 1) * 64;
        float4 ra[4], rb[4];
        if (it < 3) {
#pragma unroll
            for (int i = 0; i < 2; ++i) {
                int lin = i * 256 + t, r = lin >> 3, ch = lin & 7;
                int off = r * 256 + c0n + ((ch ^ (r & 7)) << 3);
                gl_lds16(WkN + off, &sK[cur ^ 1][lin * 8]);
                gl_lds16(WvN + off, &sV[cur ^ 1][lin * 8]);
            }
#pragma unroll
            for (int j = 0; j < 4; ++j) {
                const float* src = fb + (long)(c0n + 2 * p) * 4096 + s0 + (j * 8 + sl) * 4;
                ra[j] = *(const float4*)src;
                rb[j] = *(const float4*)(src + 4096);
            }
        }
        const char* fbase = (const char*)&sF[cur][0];
        const char* kbase = (const char*)&sK[cur][0];
        const char* vbase = (const char*)&sV[cur][0];
#pragma unroll
        for (int kk = 0; kk < 2; ++kk) {
            bf16x8 ak[4], ff[2], bv[4];
#pragma unroll
            for (int mf = 0; mf < 4; ++mf) {
                int r = mf * 16 + lr;
                ak[mf] = *(const bf16x8*)(kbase + r * 128 + (((kk * 4 + g) ^ (r & 7)) << 4));
            }
#pragma unroll
            for (int i = 0; i < 2; ++i) {
                int s = wid * 32 + i * 16 + lr;
                ff[i] = *(const bf16x8*)(fbase + s * 144 + (kk * 4 + g) * 16);
            }
#pragma unroll
            for (int nf = 0; nf < 4; ++nf) {
                int r = nf * 16 + lr;
                bv[nf] = *(const bf16x8*)(vbase + r * 128 + (((kk * 4 + g) ^ (r & 7)) << 4));
            }
#pragma unroll
            for (int mf = 0; mf < 4; ++mf)
#pragma unroll
                for (int i = 0; i < 2; ++i)
                    acc1[mf][i] = __builtin_amdgcn_mfma_f32_16x16x32_bf16(
                        ak[mf], ff[i], acc1[mf][i], 0, 0, 0);
#pragma unroll
            for (int i = 0; i < 2; ++i)
#pragma unroll
                for (int nf = 0; nf < 4; ++nf)
                    acc2[i][nf] = __builtin_amdgcn_mfma_f32_16x16x32_bf16(
                        ff[i], bv[nf], acc2[i][nf], 0, 0, 0);
        }
        if (it < 3) {
#pragma unroll
            for (int j = 0; j < 4; ++j) {
                char* base = (char*)&sF[cur ^ 1][0] + p * 4 + ((j * 8 + sl) * 4) * 144;
                *(u32*)(base +   0) = pk2(ra[j].x, rb[j].x);
                *(u32*)(base + 144) = pk2(ra[j].y, rb[j].y);
                *(u32*)(base + 288) = pk2(ra[j].z, rb[j].z);
                *(u32*)(base + 432) = pk2(ra[j].w, rb[j].w);
            }
            __syncthreads();
            cur ^= 1;
        }
    }

    bf16* kbb = kb + (long)bn * 262144;
#pragma unroll
    for (int mf = 0; mf < 4; ++mf)
#pragma unroll
        for (int i = 0; i < 2; ++i)
#pragma unroll
            for (int e = 0; e < 4; ++e) {
                int dd = mf * 16 + g * 4 + e;
                int s  = s0 + wid * 32 + i * 16 + lr;
                kbb[(long)dd * 4096 + s] = __float2bfloat16(acc1[mf][i][e]);
            }
    bf16* vtb = vT + (long)bn * 262144;
#pragma unroll
    for (int i = 0; i < 2; ++i)
#pragma unroll
        for (int nf = 0; nf < 4; ++nf)
#pragma unroll
            for (int e = 0; e < 4; ++e) {
                int s = s0 + wid * 32 + i * 16 + g * 4 + e;
                int ec = nf * 16 + lr;
                vtb[(long)s * 64 + ec] = __float2bfloat16(acc2[i][nf][e]);
            }
}

// ---------------------------------------------------------------------------
// QK^T partial + fused row sum-of-squares, 8 chunks, double-buffered. (R5)
// grid (8, 64), block 256.
// ---------------------------------------------------------------------------
__global__ __launch_bounds__(256) void qk_sum(
    const bf16* __restrict__ kb,   // [64][64][4096]
    const bf16* __restrict__ qch,  // viewed as [64][64][4096]
    float* __restrict__ part,      // [64][8][64][64]
    float* __restrict__ sumq, float* __restrict__ sumk)  // [8][4096]
{
    __shared__ bf16 sA[2][64 * 64];
    __shared__ bf16 sB[2][64 * 64];
    const int t = threadIdx.x;
    const int lane = t & 63, wid = t >> 6;
    const int wm = wid >> 1, wn = wid & 1;
    const int g = lane >> 4, lr = lane & 15;
    const int ch_ = blockIdx.x;
    const int bn = blockIdx.y;
    const bf16* kbase = kb + (long)bn * 262144;
    const bf16* qbase = qch + (long)bn * 262144;

    const int srow = t >> 1;
    const int shalf = t & 1;

    f32x4 acc[2][2];
#pragma unroll
    for (int i = 0; i < 2; ++i)
#pragma unroll
        for (int j = 0; j < 2; ++j) acc[i][j] = (f32x4){0.f, 0.f, 0.f, 0.f};
    float ss = 0.f;

    {
        int k0 = ch_ * 512;
#pragma unroll
        for (int i = 0; i < 2; ++i) {
            int lin = i * 256 + t, r = lin >> 3, c = lin & 7;
            gl_lds16(kbase + (long)r * 4096 + k0 + ((c ^ (r & 7)) << 3), &sA[0][lin * 8]);
            gl_lds16(qbase + (long)r * 4096 + k0 + ((c ^ (r & 7)) << 3), &sB[0][lin * 8]);
        }
        __syncthreads();
    }

    int cur = 0;
    for (int it = 0; it < 8; ++it) {
        if (it < 7) {
            int k0 = ch_ * 512 + (it + 1) * 64;
#pragma unroll
            for (int i = 0; i < 2; ++i) {
                int lin = i * 256 + t, r = lin >> 3, c = lin & 7;
                gl_lds16(kbase + (long)r * 4096 + k0 + ((c ^ (r & 7)) << 3), &sA[cur ^ 1][lin * 8]);
                gl_lds16(qbase + (long)r * 4096 + k0 + ((c ^ (r & 7)) << 3), &sB[cur ^ 1][lin * 8]);
            }
        }
        const char* abase = (const char*)&sA[cur][0];
        const char* bbase = (const char*)&sB[cur][0];
#pragma unroll
        for (int kk = 0; kk < 2; ++kk) {
            bf16x8 af[2], bf[2];
#pragma unroll
            for (int mf = 0; mf < 2; ++mf) {
                int r = wm * 32 + mf * 16 + lr;
                af[mf] = *(const bf16x8*)(abase + r * 128 + (((kk * 4 + g) ^ (r & 7)) << 4));
            }
#pragma unroll
            for (int nf = 0; nf < 2; ++nf) {
                int r = wn * 32 + nf * 16 + lr;
                bf[nf] = *(const bf16x8*)(bbase + r * 128 + (((kk * 4 + g) ^ (r & 7)) << 4));
            }
#pragma unroll
            for (int mf = 0; mf < 2; ++mf)
#pragma unroll
                for (int nf = 0; nf < 2; ++nf)
                    acc[mf][nf] = __builtin_amdgcn_mfma_f32_16x16x32_bf16(
                        af[mf], bf[nf], acc[mf][nf], 0, 0, 0);
        }
        {
            const char* base = (srow < 64) ? abase + srow * 128
                                           : bbase + (srow - 64) * 128;
            int r7 = srow & 7;
#pragma unroll
            for (int j = 0; j < 4; ++j) {
                bf16x8 v = *(const bf16x8*)(base + (((shalf * 4 + j) ^ r7) << 4));
#pragma unroll
                for (int e = 0; e < 8; ++e) {
                    float f = b2f((u16)v[e]);
                    ss += f * f;
                }
            }
        }
        __syncthreads();
        cur ^= 1;
    }

    ss += __shfl_xor(ss, 1);
    if (shalf == 0) {
        if (srow < 64) sumk[ch_ * 4096 + bn * 64 + srow] = ss;
        else           sumq[ch_ * 4096 + bn * 64 + srow - 64] = ss;
    }
    float* pp = part + ((long)bn * 8 + ch_) * 4096;
#pragma unroll
    for (int mf = 0; mf < 2; ++mf)
#pragma unroll
        for (int nf = 0; nf < 2; ++nf)
#pragma unroll
            for (int e = 0; e < 4; ++e) {
                int m = wm * 32 + mf * 16 + g * 4 + e;
                int nn = wn * 32 + nf * 16 + lr;
                pp[m * 64 + nn] = acc[mf][nf][e];
            }
}

// ---------------------------------------------------------------------------
// finalize: sum 8 partials, rsqrt norms, scale, softmax -> bf16  (R5)
// ---------------------------------------------------------------------------
__global__ __launch_bounds__(256) void attn_finalize_kernel(
    const float* __restrict__ part,
    const float* __restrict__ sumq, const float* __restrict__ sumk,
    const float* __restrict__ rescale,
    bf16* __restrict__ attn_out)
{
    const int bn = blockIdx.x;
    const int n = bn & 3;
    const int t = threadIdx.x;
    const float rs = rescale[n];

    __shared__ float att[64][65];
    __shared__ float rmax[64], rsum[64];
    __shared__ float iq[64], ik[64];

    if (t < 64) {
        float s = 0.f;
#pragma unroll
        for (int c = 0; c < 8; ++c) s += sumk[c * 4096 + bn * 64 + t];
        ik[t] = 1.f / fmaxf(sqrtf(s), 1e-12f);
    } else if (t < 128) {
        float s = 0.f;
#pragma unroll
        for (int c = 0; c < 8; ++c) s += sumq[c * 4096 + bn * 64 + t - 64];
        iq[t - 64] = 1.f / fmaxf(sqrtf(s), 1e-12f);
    }
    __syncthreads();

    const float* pb = part + (size_t)bn * 8 * 4096;
#pragma unroll
    for (int p = 0; p < 16; ++p) {
        int lin = p * 256 + t;
        int dd = lin >> 6, e = lin & 63;
        float v = 0.f;
#pragma unroll
        for (int c = 0; c < 8; ++c) v += pb[c * 4096 + lin];
        v *= ik[dd] * iq[e] * rs;
        att[dd][e] = v;
    }
    __syncthreads();
    if (t < 64) {
        float m = -1e30f;
        for (int e = 0; e < 64; ++e) m = fmaxf(m, att[t][e]);
        float sm = 0.f;
        for (int e = 0; e < 64; ++e) sm += expf(att[t][e] - m);
        rmax[t] = m;
        rsum[t] = 1.0f / sm;
    }
    __syncthreads();
    bf16* ob = attn_out + (size_t)bn * 4096;
#pragma unroll
    for (int p = 0; p < 16; ++p) {
        int lin = p * 256 + t;
        int dd = lin >> 6, e = lin & 63;
        ob[lin] = __float2bfloat16(expf(att[dd][e] - rmax[dd]) * rsum[dd]);
    }
}

// ---------------------------------------------------------------------------
// Fused PV + FFN, prefetched, 64-s tile. (R10)
// grid (64 s-tiles, 16 b), block 256. LDS 40 KB.
// ---------------------------------------------------------------------------
__global__ __launch_bounds__(256) void pvffn(
    const bf16* __restrict__ vT,    // [64][4096][64]
    const bf16* __restrict__ attnb, // [64][64][64]
    const bf16* __restrict__ qch,   // [16][256][4096]
    const bf16* __restrict__ Wf,    // [256][256]
    const float* __restrict__ bffn, // [256]
    float* __restrict__ out)        // [16][256][4096]
{
    __shared__ bf16 bufA[2][8192];
    __shared__ bf16 Zs[64 * 64];
    const int t = threadIdx.x;
    const int lane = t & 63, wid = t >> 6;
    const int g = lane >> 4, lr = lane & 15;
    const int s0 = blockIdx.x * 64;
    const int b = blockIdx.y;

    f32x4 accF[4][4];
#pragma unroll
    for (int i = 0; i < 4; ++i)
#pragma unroll
        for (int j = 0; j < 4; ++j) accF[i][j] = (f32x4){0.f, 0.f, 0.f, 0.f};

    {
        const int bn = b * 4;
#pragma unroll
        for (int i = 0; i < 2; ++i) {
            int lin = i * 256 + t, r = lin >> 3, c = lin & 7;
            gl_lds16(vT + (long)bn * 262144 + (long)(s0 + r) * 64 + ((c ^ (r & 7)) << 3),
                     &bufA[0][lin * 8]);
            gl_lds16(attnb + (long)bn * 4096 + r * 64 + ((c ^ (r & 7)) << 3),
                     &bufA[0][4096 + lin * 8]);
        }
        __syncthreads();
    }

    for (int n = 0; n < 4; ++n) {
        const int bn = b * 4 + n;
        const int cur = n & 1;
        if (n < 3) {
            const int bnn = bn + 1;
#pragma unroll
            for (int i = 0; i < 2; ++i) {
                int lin = i * 256 + t, r = lin >> 3, c = lin & 7;
                gl_lds16(vT + (long)bnn * 262144 + (long)(s0 + r) * 64 + ((c ^ (r & 7)) << 3),
                         &bufA[cur ^ 1][lin * 8]);
                gl_lds16(attnb + (long)bnn * 4096 + r * 64 + ((c ^ (r & 7)) << 3),
                         &bufA[cur ^ 1][4096 + lin * 8]);
            }
        }
        bf16x8 wf[2][4];
#pragma unroll
        for (int kk = 0; kk < 2; ++kk)
#pragma unroll
            for (int mf = 0; mf < 4; ++mf)
                wf[kk][mf] = *(const bf16x8*)(
                    Wf + (long)(wid * 64 + mf * 16 + lr) * 256 + n * 64 + (kk * 4 + g) * 8);

        const char* vb = (const char*)&bufA[cur][0];
        const char* ab = vb + 8192;
        f32x4 accP[4];
#pragma unroll
        for (int j = 0; j < 4; ++j) accP[j] = (f32x4){0.f, 0.f, 0.f, 0.f};
#pragma unroll
        for (int kk = 0; kk < 2; ++kk) {
            int r = wid * 16 + lr;
            bf16x8 av = *(const bf16x8*)(vb + r * 128 + (((kk * 4 + g) ^ (r & 7)) << 4));
            bf16x8 at[4];
#pragma unroll
            for (int nf = 0; nf < 4; ++nf) {
                int rr = nf * 16 + lr;
                at[nf] = *(const bf16x8*)(ab + rr * 128 + (((kk * 4 + g) ^ (rr & 7)) << 4));
            }
#pragma unroll
            for (int nf = 0; nf < 4; ++nf)
                accP[nf] = __builtin_amdgcn_mfma_f32_16x16x32_bf16(
                    av, at[nf], accP[nf], 0, 0, 0);
        }
#pragma unroll
        for (int nf = 0; nf < 4; ++nf) {
            int slb = wid * 16 + g * 4;
            int il = nf * 16 + lr;
            ushort4 qv = *(const ushort4*)(qch + ((long)b * 256 + n * 64 + il) * 4096 + s0 + slb);
            u16 qa[4] = {qv.x, qv.y, qv.z, qv.w};
#pragma unroll
            for (int e = 0; e < 4; ++e) {
                int sl = slb + e;
                float v = accP[nf][e] + b2f(qa[e]);
                bf16 hv = __float2bfloat16(v);
                int byte = sl * 128 + ((((il >> 3) ^ (sl & 7))) << 4) + (il & 7) * 2;
                *(u16*)((char*)Zs + byte) = *(u16*)&hv;
            }
        }
        __syncthreads();
#pragma unroll
        for (int kk = 0; kk < 2; ++kk) {
            bf16x8 bz[4];
#pragma unroll
            for (int nf = 0; nf < 4; ++nf) {
                int sl = nf * 16 + lr;
                bz[nf] = *(const bf16x8*)((const char*)Zs + sl * 128 + (((kk * 4 + g) ^ (sl & 7)) << 4));
            }
#pragma unroll
            for (int mf = 0; mf < 4; ++mf)
#pragma unroll
                for (int nf = 0; nf < 4; ++nf)
                    accF[mf][nf] = __builtin_amdgcn_mfma_f32_16x16x32_bf16(
                        wf[kk][mf], bz[nf], accF[mf][nf], 0, 0, 0);
        }
        __syncthreads();
    }

    float* ob = out + (long)b * 1048576;
    const bf16* qb = qch + (long)b * 1048576;
#pragma unroll
    for (int mf = 0; mf < 4; ++mf)
#pragma unroll
        for (int e = 0; e < 4; ++e) {
            int c = wid * 64 + mf * 16 + g * 4 + e;
            float bv = bffn[c];
#pragma unroll
            for (int nf = 0; nf < 4; ++nf) {
                int s = s0 + nf * 16 + lr;
                long idx = (long)c * 4096 + s;
                ob[idx] = accF[mf][nf][e] + bv + b2f(*(const u16*)(qb + idx));
            }
        }
}

// ---------------------------------------------------------------------------
__global__ __launch_bounds__(256) void wconv(
    const float* __restrict__ a, const float* __restrict__ b,
    const float* __restrict__ c, const float* __restrict__ d,
    bf16* __restrict__ o)
{
    int i = blockIdx.x * 256 + threadIdx.x;
    int which = i >> 16, off = i & 65535;
    const float* s = (which == 0) ? a : (which == 1) ? b : (which == 2) ? c : d;
    o[i] = __float2bfloat16(s[off]);
}

// ---------------------------------------------------------------------------
extern "C" void kernel_launch(void* const* d_in, const int* in_sizes, int n_in,
                              void* d_out, int out_size, void* d_ws, size_t ws_size,
                              hipStream_t stream) {
    const float* x       = (const float*)d_in[0];
    const float* fmaps   = (const float*)d_in[1];
    const float* Wq      = (const float*)d_in[2];
    const float* Wk      = (const float*)d_in[3];
    const float* Wv      = (const float*)d_in[4];
    const float* rescale = (const float*)d_in[5];
    const float* Wffn    = (const float*)d_in[6];
    const float* bffn    = (const float*)d_in[7];
    float* out = (float*)d_out;

    char* w = (char*)d_ws;
    bf16* kbuf  = (bf16*)(w + 0);             // 33.55 MB
    bf16* vT    = (bf16*)(w + 33554432L);     // 33.55 MB
    bf16* qch   = (bf16*)(w + 67108864L);     // 33.55 MB
    float* part = (float*)(w + 100663296L);   // 8.39 MB
    bf16* attnb = (bf16*)(w + 109051904L);    // 512 KB
    float* sumq = (float*)(w + 109576192L);   // 128 KB
    float* sumk = (float*)(w + 109707264L);   // 128 KB
    bf16* Wq_b  = (bf16*)(w + 109838336L);
    bf16* Wk_b  = Wq_b + 65536;
    bf16* Wv_b  = Wq_b + 131072;
    bf16* Wf_b  = Wq_b + 196608;

    dim3 blk(256);

    // 1. weights -> bf16
    wconv<<<dim3(1024), blk, 0, stream>>>(Wq, Wk, Wv, Wffn, Wq_b);
    // 2. K/V projections, fmaps read once (128-s tile, double-buffered)
    kvproj<<<dim3(32, 64), blk, 0, stream>>>(fmaps, Wk_b, Wv_b, kbuf, vT);
    // 3. Q projection (256-o tile: x read once)
    qproj8<<<dim3(32, 16), dim3(512), 0, stream>>>(x, Wq_b, qch);
    // 4. QK^T partials + fused row sumsq
    qk_sum<<<dim3(8, 64), blk, 0, stream>>>(kbuf, qch, part, sumq, sumk);
    // 5. finalize: rsqrt + scale + softmax -> attn bf16
    attn_finalize_kernel<<<dim3(64), blk, 0, stream>>>(part, sumq, sumk, rescale, attnb);
    // 6. fused PV + FFN -> out f32
    pvffn<<<dim3(64, 16), blk, 0, stream>>>(vT, attnb, qch, Wf_b, bffn, out);
}